// Round 3
// baseline (2909.011 us; speedup 1.0000x reference)
//
#include <hip/hip_runtime.h>

#define NB 4
#define SQL 1024
#define HDIM 1024
#define NHEAD 16
#define HEADD 64
#define NEXP 8
#define IDIM 2048
#define NTOK (NB*SQL)
#define CAPACITY 2048
#define ATT_SCALE 0.125f

typedef unsigned short u16;
typedef __attribute__((ext_vector_type(8))) short bf16x8;
typedef __attribute__((ext_vector_type(4))) float f32x4;

__device__ __forceinline__ u16 f2bf(float f) {
  union { float f; unsigned u; } x; x.f = f;
  unsigned r = (x.u + 0x7fffu + ((x.u >> 16) & 1u)) >> 16;
  return (u16)r;
}
__device__ __forceinline__ float bf2f(u16 b) {
  union { unsigned u; float f; } x; x.u = ((unsigned)b) << 16;
  return x.f;
}
__device__ __forceinline__ float wave_sum(float v) {
#pragma unroll
  for (int off = 32; off > 0; off >>= 1) v += __shfl_xor(v, off);
  return v;
}
__device__ __forceinline__ float wave_max(float v) {
#pragma unroll
  for (int off = 32; off > 0; off >>= 1) v = fmaxf(v, __shfl_xor(v, off));
  return v;
}

// ---------------- fp32 64x64 tiled GEMM core (vector ALU, exact fp32) ----------------
__device__ __forceinline__ void gemm_tile_f32(const float* __restrict__ A, int lda,
                                              const float* __restrict__ Bm, int ldb,
                                              int Kd, int m0, int n0,
                                              float acc[4][4])
{
  __shared__ float As[16][68];   // As[k][m]
  __shared__ float Bs[16][64];   // Bs[k][n]
  int tid = threadIdx.x;
  int tx = tid & 15, ty = tid >> 4;
  for (int k0 = 0; k0 < Kd; k0 += 16) {
#pragma unroll
    for (int p = 0; p < 4; ++p) {
      int idx = p * 256 + tid;
      int r = idx >> 4, c = idx & 15;
      As[c][r] = A[(size_t)(m0 + r) * lda + k0 + c];
    }
#pragma unroll
    for (int p = 0; p < 4; ++p) {
      int idx = p * 256 + tid;
      int kk = idx >> 6, c = idx & 63;
      Bs[kk][c] = Bm[(size_t)(k0 + kk) * ldb + n0 + c];
    }
    __syncthreads();
#pragma unroll
    for (int kk = 0; kk < 16; ++kk) {
      float4 av = *(const float4*)&As[kk][ty * 4];
      float4 bv = *(const float4*)&Bs[kk][tx * 4];
      float am[4] = {av.x, av.y, av.z, av.w};
      float bn[4] = {bv.x, bv.y, bv.z, bv.w};
#pragma unroll
      for (int i = 0; i < 4; ++i)
#pragma unroll
        for (int j = 0; j < 4; ++j)
          acc[i][j] = fmaf(am[i], bn[j], acc[i][j]);
    }
    __syncthreads();
  }
}

// ---------------- QKV projection: x@W+b, permuted stores (q,v: [B,NH,S,HD]; k: [B,NH,HD,S]) ----
__global__ __launch_bounds__(256)
void qkv_kernel(const float* __restrict__ x,
                const float* __restrict__ wq, const float* __restrict__ bq,
                const float* __restrict__ wk, const float* __restrict__ bk,
                const float* __restrict__ wv, const float* __restrict__ bv,
                float* __restrict__ q, float* __restrict__ kT, float* __restrict__ v)
{
  int mode = blockIdx.z;
  const float* W   = (mode == 0) ? wq : (mode == 1) ? wk : wv;
  const float* bia = (mode == 0) ? bq : (mode == 1) ? bk : bv;
  float acc[4][4] = {};
  int m0 = blockIdx.x * 64, n0 = blockIdx.y * 64;
  gemm_tile_f32(x, HDIM, W, HDIM, HDIM, m0, n0, acc);
  int tx = threadIdx.x & 15, ty = threadIdx.x >> 4;
#pragma unroll
  for (int i = 0; i < 4; ++i) {
    int tg = m0 + ty * 4 + i;
    int bb = tg >> 10, s = tg & 1023;
#pragma unroll
    for (int j = 0; j < 4; ++j) {
      int cg = n0 + tx * 4 + j;
      int hh = cg >> 6, d = cg & 63;
      float val = acc[i][j] + bia[cg];
      int bh = bb * NHEAD + hh;
      if (mode == 0)      q[((size_t)bh * SQL + s) * HEADD + d] = val;
      else if (mode == 1) kT[((size_t)bh * HEADD + d) * SQL + s] = val;
      else                v[((size_t)bh * SQL + s) * HEADD + d] = val;
    }
  }
}

// ---------------- O-projection ----------------
__global__ __launch_bounds__(256)
void proj_kernel(const float* __restrict__ ao, const float* __restrict__ ow,
                 const float* __restrict__ ob, float* __restrict__ out)
{
  float acc[4][4] = {};
  int m0 = blockIdx.x * 64, n0 = blockIdx.y * 64;
  gemm_tile_f32(ao, HDIM, ow, HDIM, HDIM, m0, n0, acc);
  int tx = threadIdx.x & 15, ty = threadIdx.x >> 4;
#pragma unroll
  for (int i = 0; i < 4; ++i)
#pragma unroll
    for (int j = 0; j < 4; ++j) {
      int cg = n0 + tx * 4 + j;
      out[(size_t)(m0 + ty * 4 + i) * HDIM + cg] = acc[i][j] + ob[cg];
    }
}

// ---------------- causal attention, fp32, one wave per query row ----------------
__global__ __launch_bounds__(256)
void attn_kernel(const float* __restrict__ q, const float* __restrict__ kT,
                 const float* __restrict__ v, float* __restrict__ ao)
{
  __shared__ float qs[4][64];
  __shared__ float ps[4][1024];
  int w = threadIdx.x >> 6, l = threadIdx.x & 63;
  int rid = blockIdx.x * 4 + w;          // rid = bh*S + sq
  int bh = rid >> 10, sq = rid & 1023;
  qs[w][l] = q[(size_t)rid * HEADD + l];
  __syncthreads();
  int nk = sq + 1;                       // causal: k <= sq
  const float* kTb = kT + (size_t)bh * HEADD * SQL;
  float lmax = -1e30f;
  for (int kb = 0; kb < nk; kb += 64) {
    int k = kb + l;
    float sv = -1e30f;
    if (k < nk) {
      float sum = 0.f;
#pragma unroll 8
      for (int d = 0; d < 64; ++d) sum += qs[w][d] * kTb[d * SQL + k];
      sv = sum * ATT_SCALE;
      lmax = fmaxf(lmax, sv);
    }
    ps[w][kb + l] = sv;
  }
  lmax = wave_max(lmax);
  float lsum = 0.f;
  for (int kb = 0; kb < nk; kb += 64) {
    int k = kb + l;
    if (k < nk) {
      float e = expf(ps[w][k] - lmax);
      ps[w][k] = e;
      lsum += e;
    }
  }
  lsum = wave_sum(lsum);
  __syncthreads();
  const float* vb_ = v + (size_t)bh * SQL * HEADD + l;
  float acc = 0.f;
  int k = 0;
  for (; k + 4 <= nk; k += 4) {
    acc += ps[w][k]     * vb_[(size_t)(k)     * HEADD];
    acc += ps[w][k + 1] * vb_[(size_t)(k + 1) * HEADD];
    acc += ps[w][k + 2] * vb_[(size_t)(k + 2) * HEADD];
    acc += ps[w][k + 3] * vb_[(size_t)(k + 3) * HEADD];
  }
  for (; k < nk; ++k) acc += ps[w][k] * vb_[(size_t)k * HEADD];
  int b = bh >> 4, hh = bh & 15;
  ao[((size_t)(b * SQL + sq)) * HDIM + hh * HEADD + l] = acc / lsum;
}

// ---------------- residual + RMSNorm ----------------
__global__ __launch_bounds__(256)
void rmsnorm_kernel(const float* __restrict__ x, const float* __restrict__ p,
                    const float* __restrict__ w, float* __restrict__ out)
{
  int t = blockIdx.x, tid = threadIdx.x;
  float4 xv = ((const float4*)(x + (size_t)t * HDIM))[tid];
  float4 pv = ((const float4*)(p + (size_t)t * HDIM))[tid];
  float4 s = {xv.x + pv.x, xv.y + pv.y, xv.z + pv.z, xv.w + pv.w};
  float ss = s.x * s.x + s.y * s.y + s.z * s.z + s.w * s.w;
  __shared__ float red[4];
  float wsv = wave_sum(ss);
  int wid = tid >> 6, l = tid & 63;
  if (l == 0) red[wid] = wsv;
  __syncthreads();
  float tot = red[0] + red[1] + red[2] + red[3];
  float inv = 1.0f / sqrtf(tot / (float)HDIM + 1e-6f);
  float4 wv = ((const float4*)w)[tid];
  float4 o = {s.x * inv * wv.x, s.y * inv * wv.y, s.z * inv * wv.z, s.w * inv * wv.w};
  ((float4*)(out + (size_t)t * HDIM))[tid] = o;
}

// ---------------- router: logits, softmax, top-2, weight norm ----------------
__global__ __launch_bounds__(256)
void router_kernel(const float* __restrict__ h, const float* __restrict__ gw,
                   int* __restrict__ ti, float* __restrict__ tw)
{
  int wid = threadIdx.x >> 6, l = threadIdx.x & 63;
  int t = blockIdx.x * 4 + wid;
  const float* hr = h + (size_t)t * HDIM;
  float hv[16];
#pragma unroll
  for (int j = 0; j < 16; ++j) hv[j] = hr[l + 64 * j];
  float lg[NEXP];
#pragma unroll
  for (int e = 0; e < NEXP; ++e) {
    const float* g = gw + (size_t)e * HDIM;
    float p = 0.f;
#pragma unroll
    for (int j = 0; j < 16; ++j) p += hv[j] * g[l + 64 * j];
    lg[e] = wave_sum(p);
  }
  if (l == 0) {
    int i1 = 0; float m1 = lg[0];
#pragma unroll
    for (int e = 1; e < NEXP; ++e) if (lg[e] > m1) { m1 = lg[e]; i1 = e; }
    int i2 = 0; float m2 = -1e30f;
#pragma unroll
    for (int e = 0; e < NEXP; ++e) if (e != i1 && lg[e] > m2) { m2 = lg[e]; i2 = e; }
    float se = 0.f;
#pragma unroll
    for (int e = 0; e < NEXP; ++e) se += expf(lg[e] - m1);
    float p1 = 1.0f / se;
    float p2 = expf(m2 - m1) / se;
    float denom = p1 + p2 + 1e-20f;
    tw[t * 2]     = p1 / denom * 0.5f;
    tw[t * 2 + 1] = p2 / denom * 0.5f;
    ti[t * 2]     = i1;
    ti[t * 2 + 1] = i2;
  }
}

// ---------------- deterministic capacity scan (flat order t*K+k), one wave ----------------
__global__ void scan_kernel(const int* __restrict__ ti, int* __restrict__ eidx,
                            int* __restrict__ counts, int* __restrict__ slotmap)
{
  int l = threadIdx.x;
  int base[NEXP] = {0, 0, 0, 0, 0, 0, 0, 0};
  unsigned long long below = (l == 0) ? 0ull : ((~0ull) >> (64 - l));
  for (int c2 = 0; c2 < (NTOK * 2) / 64; ++c2) {
    int f = c2 * 64 + l;
    int e = ti[f];
    int mypos = 0;
#pragma unroll
    for (int e0 = 0; e0 < NEXP; ++e0) {
      unsigned long long m = __ballot(e == e0);
      if (e == e0) mypos = base[e0] + __popcll(m & below);
      base[e0] += __popcll(m);
    }
    int slot;
    if (mypos < CAPACITY) {
      slot = e * CAPACITY + mypos;
      eidx[slot] = f >> 1;               // token index
    } else slot = -1;
    slotmap[f] = slot;
  }
  if (l < NEXP) counts[l] = (base[l] < CAPACITY) ? base[l] : CAPACITY;
}

// ---------------- MoE GEMM1 (gathered h @ w1[e] + b1 -> gelu), bf16 MFMA ----------------
__global__ __launch_bounds__(256)
void moe_gemm1_kernel(const float* __restrict__ h, const float* __restrict__ w1,
                      const float* __restrict__ b1, const int* __restrict__ eidx,
                      const int* __restrict__ counts, u16* __restrict__ h1)
{
  int e = blockIdx.z;
  int cnt = counts[e];
  int m0 = blockIdx.x * 64;
  if (m0 >= cnt) return;
  int n0 = blockIdx.y * 64;
  __shared__ __align__(16) u16 As[64 * 40];   // [row][k]
  __shared__ __align__(16) u16 Bs[64 * 40];   // [n][k]
  __shared__ int rowtok[64];
  int tid = threadIdx.x;
  if (tid < 64) {
    int r = m0 + tid;
    rowtok[tid] = (r < cnt) ? eidx[e * CAPACITY + r] : -1;
  }
  __syncthreads();
  const float* w1e = w1 + (size_t)e * HDIM * IDIM;
  const float* b1e = b1 + (size_t)e * IDIM;
  f32x4 acc[4];
#pragma unroll
  for (int nt = 0; nt < 4; ++nt) acc[nt] = (f32x4){0.f, 0.f, 0.f, 0.f};
  int w = tid >> 6, l = tid & 63;
  int lr = l & 15, lq = l >> 4;
  for (int k0 = 0; k0 < HDIM; k0 += 32) {
#pragma unroll
    for (int p = 0; p < 8; ++p) {
      int idx = p * 256 + tid;
      int r = idx >> 5, c = idx & 31;
      int tok = rowtok[r];
      float vv = (tok >= 0) ? h[(size_t)tok * HDIM + k0 + c] : 0.0f;
      As[r * 40 + c] = f2bf(vv);
    }
#pragma unroll
    for (int p = 0; p < 8; ++p) {
      int idx = p * 256 + tid;
      int kk = idx >> 6, nn = idx & 63;
      Bs[nn * 40 + kk] = f2bf(w1e[(size_t)(k0 + kk) * IDIM + n0 + nn]);
    }
    __syncthreads();
    bf16x8 av = *(const bf16x8*)&As[(w * 16 + lr) * 40 + lq * 8];
#pragma unroll
    for (int nt = 0; nt < 4; ++nt) {
      bf16x8 bv = *(const bf16x8*)&Bs[(nt * 16 + lr) * 40 + lq * 8];
      acc[nt] = __builtin_amdgcn_mfma_f32_16x16x32_bf16(av, bv, acc[nt], 0, 0, 0);
    }
    __syncthreads();
  }
  u16* h1e = h1 + (size_t)e * CAPACITY * IDIM;
#pragma unroll
  for (int nt = 0; nt < 4; ++nt) {
    int colg = n0 + nt * 16 + lr;
    float bb = b1e[colg];
#pragma unroll
    for (int i = 0; i < 4; ++i) {
      int rowg = m0 + w * 16 + lq * 4 + i;
      float y = acc[nt][i] + bb;
      float g = 0.5f * y * (1.0f + erff(y * 0.70710678118654752f));
      h1e[(size_t)rowg * IDIM + colg] = f2bf(g);
    }
  }
}

// ---------------- MoE GEMM2 (h1 @ w2[e] + b2 -> ybuf), bf16 MFMA ----------------
__global__ __launch_bounds__(256)
void moe_gemm2_kernel(const u16* __restrict__ h1, const float* __restrict__ w2,
                      const float* __restrict__ b2, const int* __restrict__ counts,
                      u16* __restrict__ ybuf)
{
  int e = blockIdx.z;
  int cnt = counts[e];
  int m0 = blockIdx.x * 64;
  if (m0 >= cnt) return;
  int n0 = blockIdx.y * 64;
  __shared__ __align__(16) u16 As[64 * 40];
  __shared__ __align__(16) u16 Bs[64 * 40];
  int tid = threadIdx.x;
  const u16* h1e = h1 + (size_t)e * CAPACITY * IDIM;
  const float* w2e = w2 + (size_t)e * IDIM * HDIM;
  const float* b2e = b2 + (size_t)e * HDIM;
  f32x4 acc[4];
#pragma unroll
  for (int nt = 0; nt < 4; ++nt) acc[nt] = (f32x4){0.f, 0.f, 0.f, 0.f};
  int w = tid >> 6, l = tid & 63;
  int lr = l & 15, lq = l >> 4;
  for (int k0 = 0; k0 < IDIM; k0 += 32) {
#pragma unroll
    for (int p = 0; p < 8; ++p) {
      int idx = p * 256 + tid;
      int r = idx >> 5, c = idx & 31;
      int rowg = m0 + r;
      As[r * 40 + c] = (rowg < cnt) ? h1e[(size_t)rowg * IDIM + k0 + c] : (u16)0;
    }
#pragma unroll
    for (int p = 0; p < 8; ++p) {
      int idx = p * 256 + tid;
      int kk = idx >> 6, nn = idx & 63;
      Bs[nn * 40 + kk] = f2bf(w2e[(size_t)(k0 + kk) * HDIM + n0 + nn]);
    }
    __syncthreads();
    bf16x8 av = *(const bf16x8*)&As[(w * 16 + lr) * 40 + lq * 8];
#pragma unroll
    for (int nt = 0; nt < 4; ++nt) {
      bf16x8 bv = *(const bf16x8*)&Bs[(nt * 16 + lr) * 40 + lq * 8];
      acc[nt] = __builtin_amdgcn_mfma_f32_16x16x32_bf16(av, bv, acc[nt], 0, 0, 0);
    }
    __syncthreads();
  }
#pragma unroll
  for (int nt = 0; nt < 4; ++nt) {
    int colg = n0 + nt * 16 + lr;
    float bb = b2e[colg];
#pragma unroll
    for (int i = 0; i < 4; ++i) {
      int slot = m0 + w * 16 + lq * 4 + i;
      if (slot < cnt)
        ybuf[((size_t)e * CAPACITY + slot) * HDIM + colg] = f2bf(acc[nt][i] + bb);
    }
  }
}

// ---------------- final: h + sum_k tw_k * y[slot_k] -> LayerNorm -> fp32 out ----------------
__global__ __launch_bounds__(256)
void final_kernel(const float* __restrict__ h, const u16* __restrict__ ybuf,
                  const int* __restrict__ slotmap, const float* __restrict__ tw,
                  const float* __restrict__ lnw, const float* __restrict__ lnb,
                  float* __restrict__ out)
{
  int t = blockIdx.x, tid = threadIdx.x;
  int s0 = slotmap[t * 2], s1 = slotmap[t * 2 + 1];
  float w0 = tw[t * 2], w1v = tw[t * 2 + 1];
  float4 hv = ((const float4*)(h + (size_t)t * HDIM))[tid];
  float vals[4] = {hv.x, hv.y, hv.z, hv.w};
  if (s0 >= 0) {
    const u16* yr = ybuf + (size_t)s0 * HDIM + tid * 4;
#pragma unroll
    for (int j = 0; j < 4; ++j) vals[j] += w0 * bf2f(yr[j]);
  }
  if (s1 >= 0) {
    const u16* yr = ybuf + (size_t)s1 * HDIM + tid * 4;
#pragma unroll
    for (int j = 0; j < 4; ++j) vals[j] += w1v * bf2f(yr[j]);
  }
  float s = vals[0] + vals[1] + vals[2] + vals[3];
  float q2 = vals[0] * vals[0] + vals[1] * vals[1] + vals[2] * vals[2] + vals[3] * vals[3];
  __shared__ float reds[4], redq[4];
  float wsv = wave_sum(s), wqv = wave_sum(q2);
  int wid = tid >> 6, l = tid & 63;
  if (l == 0) { reds[wid] = wsv; redq[wid] = wqv; }
  __syncthreads();
  float tot = reds[0] + reds[1] + reds[2] + reds[3];
  float totq = redq[0] + redq[1] + redq[2] + redq[3];
  float mu = tot / 1024.0f;
  float var = totq / 1024.0f - mu * mu;
  float inv = 1.0f / sqrtf(var + 1e-6f);
#pragma unroll
  for (int j = 0; j < 4; ++j) {
    int c = tid * 4 + j;
    out[(size_t)t * HDIM + c] = (vals[j] - mu) * inv * lnw[c] + lnb[c];
  }
}

extern "C" void kernel_launch(void* const* d_in, const int* in_sizes, int n_in,
                              void* d_out, int out_size, void* d_ws, size_t ws_size,
                              hipStream_t stream)
{
  const float* x      = (const float*)d_in[0];
  // d_in[1] = attn_mask (causal additive) — applied analytically via k<=q
  const float* qw     = (const float*)d_in[2];
  const float* qb     = (const float*)d_in[3];
  const float* kw     = (const float*)d_in[4];
  const float* kb     = (const float*)d_in[5];
  const float* vw     = (const float*)d_in[6];
  const float* vb     = (const float*)d_in[7];
  const float* ow     = (const float*)d_in[8];
  const float* ob     = (const float*)d_in[9];
  const float* rms_w  = (const float*)d_in[10];
  const float* gate_w = (const float*)d_in[11];
  const float* w1     = (const float*)d_in[12];
  const float* b1     = (const float*)d_in[13];
  const float* w2     = (const float*)d_in[14];
  const float* b2     = (const float*)d_in[15];
  const float* ln_w   = (const float*)d_in[16];
  const float* ln_b   = (const float*)d_in[17];

  char* ws = (char*)d_ws;
  const size_t MB = 1024ull * 1024ull;
  float* qbuf   = (float*)(ws + 0 * MB);     // 16MB, then reused as proj
  float* kTbuf  = (float*)(ws + 16 * MB);    // 16MB, then reused as h
  float* vbuf   = (float*)(ws + 32 * MB);    // 16MB
  float* aobuf  = (float*)(ws + 48 * MB);    // 16MB
  u16*   h1buf  = (u16*)(ws + 32 * MB);      // 64MB, overlaps dead v/ao
  u16*   ybuf   = (u16*)(ws + 96 * MB);      // 32MB
  char*  sm     = ws + 128 * MB;
  int*   ti      = (int*)(sm);
  float* tw      = (float*)(sm + 32 * 1024);
  int*   eidx    = (int*)(sm + 64 * 1024);
  int*   slotmap = (int*)(sm + 128 * 1024);
  int*   counts  = (int*)(sm + 160 * 1024);
  float* projbuf = qbuf;
  float* hbuf    = kTbuf;

  qkv_kernel<<<dim3(NTOK / 64, HDIM / 64, 3), 256, 0, stream>>>(
      x, qw, qb, kw, kb, vw, vb, qbuf, kTbuf, vbuf);
  attn_kernel<<<NB * NHEAD * SQL / 4, 256, 0, stream>>>(qbuf, kTbuf, vbuf, aobuf);
  proj_kernel<<<dim3(NTOK / 64, HDIM / 64), 256, 0, stream>>>(aobuf, ow, ob, projbuf);
  rmsnorm_kernel<<<NTOK, 256, 0, stream>>>(x, projbuf, rms_w, hbuf);
  router_kernel<<<NTOK / 4, 256, 0, stream>>>(hbuf, gate_w, ti, tw);
  scan_kernel<<<1, 64, 0, stream>>>(ti, eidx, counts, slotmap);
  moe_gemm1_kernel<<<dim3(CAPACITY / 64, IDIM / 64, NEXP), 256, 0, stream>>>(
      hbuf, w1, b1, eidx, counts, h1buf);
  moe_gemm2_kernel<<<dim3(CAPACITY / 64, HDIM / 64, NEXP), 256, 0, stream>>>(
      h1buf, w2, b2, counts, ybuf);
  final_kernel<<<NTOK, 256, 0, stream>>>(hbuf, ybuf, slotmap, tw, ln_w, ln_b,
                                         (float*)d_out);
}

// Round 4
// 1674.619 us; speedup vs baseline: 1.7371x; 1.7371x over previous
//
#include <hip/hip_runtime.h>

#define NB 4
#define SQL 1024
#define HDIM 1024
#define NHEAD 16
#define HEADD 64
#define NEXP 8
#define IDIM 2048
#define NTOK (NB*SQL)
#define CAPACITY 2048
#define ATT_SCALE 0.125f

typedef unsigned short u16;
typedef __attribute__((ext_vector_type(8))) short bf16x8;
typedef __attribute__((ext_vector_type(4))) float f32x4;

__device__ __forceinline__ u16 f2bf(float f) {
  union { float f; unsigned u; } x; x.f = f;
  unsigned r = (x.u + 0x7fffu + ((x.u >> 16) & 1u)) >> 16;
  return (u16)r;
}
__device__ __forceinline__ float bf2f(u16 b) {
  union { unsigned u; float f; } x; x.u = ((unsigned)b) << 16;
  return x.f;
}
__device__ __forceinline__ float wave_sum(float v) {
#pragma unroll
  for (int off = 32; off > 0; off >>= 1) v += __shfl_xor(v, off);
  return v;
}
__device__ __forceinline__ float wave_max(float v) {
#pragma unroll
  for (int off = 32; off > 0; off >>= 1) v = fmaxf(v, __shfl_xor(v, off));
  return v;
}

// ---------------- fp32 128x128 tiled GEMM core (vector ALU, exact fp32) ----------------
// acc[8][8] per thread; thread (tx=tid&15, ty=tid>>4) owns rows m0+ty*8.., cols n0+tx*8..
__device__ __forceinline__ void gemm_f32_128(const float* __restrict__ A, int lda,
                                             const float* __restrict__ Bm, int ldb,
                                             int Kd, int m0, int n0, float acc[8][8])
{
  __shared__ float As[16 * 132];   // [k][m], stride 132
  __shared__ float Bs[16 * 132];   // [k][n], stride 132
  int tid = threadIdx.x;
  int tx = tid & 15, ty = tid >> 4;
  for (int k0 = 0; k0 < Kd; k0 += 16) {
#pragma unroll
    for (int p = 0; p < 2; ++p) {
      int flat = p * 256 + tid;
      int m = flat >> 2, kc = (flat & 3) * 4;
      float4 av = *(const float4*)&A[(size_t)(m0 + m) * lda + k0 + kc];
      As[(kc + 0) * 132 + m] = av.x;
      As[(kc + 1) * 132 + m] = av.y;
      As[(kc + 2) * 132 + m] = av.z;
      As[(kc + 3) * 132 + m] = av.w;
      int kk = flat >> 5, nc = (flat & 31) * 4;
      float4 bv = *(const float4*)&Bm[(size_t)(k0 + kk) * ldb + n0 + nc];
      *(float4*)&Bs[kk * 132 + nc] = bv;
    }
    __syncthreads();
#pragma unroll
    for (int kk = 0; kk < 16; ++kk) {
      float a[8], b[8];
      *(float4*)&a[0] = *(const float4*)&As[kk * 132 + ty * 8];
      *(float4*)&a[4] = *(const float4*)&As[kk * 132 + ty * 8 + 4];
      *(float4*)&b[0] = *(const float4*)&Bs[kk * 132 + tx * 8];
      *(float4*)&b[4] = *(const float4*)&Bs[kk * 132 + tx * 8 + 4];
#pragma unroll
      for (int i = 0; i < 8; ++i)
#pragma unroll
        for (int j = 0; j < 8; ++j)
          acc[i][j] = fmaf(a[i], b[j], acc[i][j]);
    }
    __syncthreads();
  }
}

// ---------------- QKV projection: x@W+b, permuted stores (q,v: [B,NH,S,HD]; k: [B,NH,HD,S]) ----
__global__ __launch_bounds__(256)
void qkv_kernel(const float* __restrict__ x,
                const float* __restrict__ wq, const float* __restrict__ bq,
                const float* __restrict__ wk, const float* __restrict__ bk,
                const float* __restrict__ wv, const float* __restrict__ bv,
                float* __restrict__ q, float* __restrict__ kT, float* __restrict__ v)
{
  int mode = blockIdx.z;
  const float* W   = (mode == 0) ? wq : (mode == 1) ? wk : wv;
  const float* bia = (mode == 0) ? bq : (mode == 1) ? bk : bv;
  float acc[8][8];
#pragma unroll
  for (int i = 0; i < 8; ++i)
#pragma unroll
    for (int j = 0; j < 8; ++j) acc[i][j] = 0.f;
  int m0 = blockIdx.x * 128, n0 = blockIdx.y * 128;
  gemm_f32_128(x, HDIM, W, HDIM, HDIM, m0, n0, acc);
  int tx = threadIdx.x & 15, ty = threadIdx.x >> 4;
#pragma unroll
  for (int i = 0; i < 8; ++i) {
    int tg = m0 + ty * 8 + i;
    int bb = tg >> 10, s = tg & 1023;
#pragma unroll
    for (int j = 0; j < 8; ++j) {
      int cg = n0 + tx * 8 + j;
      int hh = cg >> 6, d = cg & 63;
      float val = acc[i][j] + bia[cg];
      int bh = bb * NHEAD + hh;
      if (mode == 0)      q[((size_t)bh * SQL + s) * HEADD + d] = val;
      else if (mode == 1) kT[((size_t)bh * HEADD + d) * SQL + s] = val;
      else                v[((size_t)bh * SQL + s) * HEADD + d] = val;
    }
  }
}

// ---------------- O-projection ----------------
__global__ __launch_bounds__(256)
void proj_kernel(const float* __restrict__ ao, const float* __restrict__ ow,
                 const float* __restrict__ ob, float* __restrict__ out)
{
  float acc[8][8];
#pragma unroll
  for (int i = 0; i < 8; ++i)
#pragma unroll
    for (int j = 0; j < 8; ++j) acc[i][j] = 0.f;
  int m0 = blockIdx.x * 128, n0 = blockIdx.y * 128;
  gemm_f32_128(ao, HDIM, ow, HDIM, HDIM, m0, n0, acc);
  int tx = threadIdx.x & 15, ty = threadIdx.x >> 4;
#pragma unroll
  for (int i = 0; i < 8; ++i)
#pragma unroll
    for (int j = 0; j < 8; ++j) {
      int cg = n0 + tx * 8 + j;
      out[(size_t)(m0 + ty * 8 + i) * HDIM + cg] = acc[i][j] + ob[cg];
    }
}

// ---------------- causal attention, fp32, one wave per query row ----------------
__global__ __launch_bounds__(256)
void attn_kernel(const float* __restrict__ q, const float* __restrict__ kT,
                 const float* __restrict__ v, float* __restrict__ ao)
{
  __shared__ float qs[4][64];
  __shared__ float ps[4][1024];
  int w = threadIdx.x >> 6, l = threadIdx.x & 63;
  int rid = blockIdx.x * 4 + w;          // rid = bh*S + sq
  int bh = rid >> 10, sq = rid & 1023;
  qs[w][l] = q[(size_t)rid * HEADD + l];
  __syncthreads();
  int nk = sq + 1;                       // causal: k <= sq
  const float* kTb = kT + (size_t)bh * HEADD * SQL;
  float lmax = -1e30f;
  for (int kb = 0; kb < nk; kb += 64) {
    int k = kb + l;
    float sv = -1e30f;
    if (k < nk) {
      float sum = 0.f;
#pragma unroll 8
      for (int d = 0; d < 64; ++d) sum += qs[w][d] * kTb[d * SQL + k];
      sv = sum * ATT_SCALE;
      lmax = fmaxf(lmax, sv);
    }
    ps[w][kb + l] = sv;
  }
  lmax = wave_max(lmax);
  float lsum = 0.f;
  for (int kb = 0; kb < nk; kb += 64) {
    int k = kb + l;
    if (k < nk) {
      float e = expf(ps[w][k] - lmax);
      ps[w][k] = e;
      lsum += e;
    }
  }
  lsum = wave_sum(lsum);
  __syncthreads();
  const float* vb_ = v + (size_t)bh * SQL * HEADD + l;
  float acc = 0.f;
  int k = 0;
  for (; k + 4 <= nk; k += 4) {
    acc += ps[w][k]     * vb_[(size_t)(k)     * HEADD];
    acc += ps[w][k + 1] * vb_[(size_t)(k + 1) * HEADD];
    acc += ps[w][k + 2] * vb_[(size_t)(k + 2) * HEADD];
    acc += ps[w][k + 3] * vb_[(size_t)(k + 3) * HEADD];
  }
  for (; k < nk; ++k) acc += ps[w][k] * vb_[(size_t)k * HEADD];
  int b = bh >> 4, hh = bh & 15;
  ao[((size_t)(b * SQL + sq)) * HDIM + hh * HEADD + l] = acc / lsum;
}

// ---------------- residual + RMSNorm (fp32 h out + bf16 copy) ----------------
__global__ __launch_bounds__(256)
void rmsnorm_kernel(const float* __restrict__ x, const float* __restrict__ p,
                    const float* __restrict__ w, float* __restrict__ out,
                    u16* __restrict__ outbf)
{
  int t = blockIdx.x, tid = threadIdx.x;
  float4 xv = ((const float4*)(x + (size_t)t * HDIM))[tid];
  float4 pv = ((const float4*)(p + (size_t)t * HDIM))[tid];
  float4 s = {xv.x + pv.x, xv.y + pv.y, xv.z + pv.z, xv.w + pv.w};
  float ss = s.x * s.x + s.y * s.y + s.z * s.z + s.w * s.w;
  __shared__ float red[4];
  float wsv = wave_sum(ss);
  int wid = tid >> 6, l = tid & 63;
  if (l == 0) red[wid] = wsv;
  __syncthreads();
  float tot = red[0] + red[1] + red[2] + red[3];
  float inv = 1.0f / sqrtf(tot / (float)HDIM + 1e-6f);
  float4 wv = ((const float4*)w)[tid];
  float4 o = {s.x * inv * wv.x, s.y * inv * wv.y, s.z * inv * wv.z, s.w * inv * wv.w};
  ((float4*)(out + (size_t)t * HDIM))[tid] = o;
  ushort4 ob = {f2bf(o.x), f2bf(o.y), f2bf(o.z), f2bf(o.w)};
  ((ushort4*)(outbf + (size_t)t * HDIM))[tid] = ob;
}

// ---------------- transpose+convert: in fp32 [e][R][C] -> out bf16 [e][C][R] ----------------
__global__ __launch_bounds__(256)
void transpose_cvt_kernel(const float* __restrict__ in, u16* __restrict__ out,
                          int R, int C)
{
  int e = blockIdx.z;
  const float* ine = in + (size_t)e * R * C;
  u16* oute = out + (size_t)e * R * C;
  __shared__ u16 Ts[32 * 34];
  int tx = threadIdx.x & 31, ty = threadIdx.x >> 5;
  int r0 = blockIdx.y * 32, c0 = blockIdx.x * 32;
#pragma unroll
  for (int qq = 0; qq < 4; ++qq) {
    int rr = ty + qq * 8;
    Ts[tx * 34 + rr] = f2bf(ine[(size_t)(r0 + rr) * C + c0 + tx]);
  }
  __syncthreads();
#pragma unroll
  for (int qq = 0; qq < 4; ++qq) {
    int cc = ty + qq * 8;
    oute[(size_t)(c0 + cc) * R + r0 + tx] = Ts[cc * 34 + tx];
  }
}

// ---------------- router: logits, softmax, top-2, weight norm ----------------
__global__ __launch_bounds__(256)
void router_kernel(const float* __restrict__ h, const float* __restrict__ gw,
                   int* __restrict__ ti, float* __restrict__ tw)
{
  int wid = threadIdx.x >> 6, l = threadIdx.x & 63;
  int t = blockIdx.x * 4 + wid;
  const float* hr = h + (size_t)t * HDIM;
  float hv[16];
#pragma unroll
  for (int j = 0; j < 16; ++j) hv[j] = hr[l + 64 * j];
  float lg[NEXP];
#pragma unroll
  for (int e = 0; e < NEXP; ++e) {
    const float* g = gw + (size_t)e * HDIM;
    float p = 0.f;
#pragma unroll
    for (int j = 0; j < 16; ++j) p += hv[j] * g[l + 64 * j];
    lg[e] = wave_sum(p);
  }
  if (l == 0) {
    int i1 = 0; float m1 = lg[0];
#pragma unroll
    for (int e = 1; e < NEXP; ++e) if (lg[e] > m1) { m1 = lg[e]; i1 = e; }
    int i2 = 0; float m2 = -1e30f;
#pragma unroll
    for (int e = 0; e < NEXP; ++e) if (e != i1 && lg[e] > m2) { m2 = lg[e]; i2 = e; }
    float se = 0.f;
#pragma unroll
    for (int e = 0; e < NEXP; ++e) se += expf(lg[e] - m1);
    float p1 = 1.0f / se;
    float p2 = expf(m2 - m1) / se;
    float denom = p1 + p2 + 1e-20f;
    tw[t * 2]     = p1 / denom * 0.5f;
    tw[t * 2 + 1] = p2 / denom * 0.5f;
    ti[t * 2]     = i1;
    ti[t * 2 + 1] = i2;
  }
}

// ---------------- deterministic capacity scan + packed-row bases ----------------
__global__ void scan_kernel(const int* __restrict__ ti, int* __restrict__ eidx,
                            int* __restrict__ counts, int* __restrict__ slotmap,
                            int* __restrict__ ebase)
{
  int l = threadIdx.x;
  int base[NEXP] = {0, 0, 0, 0, 0, 0, 0, 0};
  unsigned long long below = (l == 0) ? 0ull : ((~0ull) >> (64 - l));
  for (int c2 = 0; c2 < (NTOK * 2) / 64; ++c2) {
    int f = c2 * 64 + l;
    int e = ti[f];
    int mypos = 0;
#pragma unroll
    for (int e0 = 0; e0 < NEXP; ++e0) {
      unsigned long long m = __ballot(e == e0);
      if (e == e0) mypos = base[e0] + __popcll(m & below);
      base[e0] += __popcll(m);
    }
    int slot;
    if (mypos < CAPACITY) {
      slot = e * CAPACITY + mypos;
      eidx[slot] = f >> 1;               // token index
    } else slot = -1;
    slotmap[f] = slot;
  }
  int eb[NEXP]; int run = 0;
#pragma unroll
  for (int e = 0; e < NEXP; ++e) {
    eb[e] = run;
    run += (base[e] < CAPACITY) ? base[e] : CAPACITY;
  }
  if (l < NEXP) {
    counts[l] = (base[l] < CAPACITY) ? base[l] : CAPACITY;
    ebase[l] = eb[l];
  }
  // remap slotmap -> packed global rows
  for (int c2 = 0; c2 < (NTOK * 2) / 64; ++c2) {
    int f = c2 * 64 + l;
    int vv = slotmap[f];
    if (vv >= 0) slotmap[f] = eb[vv >> 11] + (vv & (CAPACITY - 1));
  }
}

// ---------------- MoE GEMM1: gathered hbf @ w1T[e] + b1 -> gelu -> h1 (packed rows) ------
__global__ __launch_bounds__(256)
void moe_gemm1_kernel(const u16* __restrict__ hbf, const u16* __restrict__ w1T,
                      const float* __restrict__ b1, const int* __restrict__ eidx,
                      const int* __restrict__ counts, const int* __restrict__ ebase,
                      u16* __restrict__ h1)
{
  int e = blockIdx.z;
  int cnt = counts[e];
  int m0 = blockIdx.x * 128;
  if (m0 >= cnt) return;
  int n0 = blockIdx.y * 128;
  int base = ebase[e];
  __shared__ __align__(16) u16 As[128 * 64];   // [row][8 chunks of 8], XOR-swizzled
  __shared__ __align__(16) u16 Bs[128 * 64];
  __shared__ int rowtok[128];
  int tid = threadIdx.x;
  if (tid < 128) {
    int r = m0 + tid;
    rowtok[tid] = (r < cnt) ? eidx[e * CAPACITY + r] : -1;
  }
  __syncthreads();
  const u16* BT = w1T + (size_t)e * IDIM * HDIM;   // [IDIM][HDIM]
  f32x4 acc[4][4];
#pragma unroll
  for (int i = 0; i < 4; ++i)
#pragma unroll
    for (int j = 0; j < 4; ++j) acc[i][j] = (f32x4){0.f, 0.f, 0.f, 0.f};
  int w = tid >> 6, l = tid & 63;
  int lr = l & 15, lq = l >> 4;
  int wm = (w & 1) * 64, wn = (w >> 1) * 64;
  for (int k0 = 0; k0 < HDIM; k0 += 64) {
#pragma unroll
    for (int p = 0; p < 4; ++p) {
      int flat = p * 256 + tid;
      int r = flat >> 3, c = flat & 7;
      int tok = rowtok[r];
      uint4 a4 = {0u, 0u, 0u, 0u};
      if (tok >= 0) a4 = *(const uint4*)&hbf[(size_t)tok * HDIM + k0 + c * 8];
      *(uint4*)&As[(r * 8 + (c ^ (r & 7))) * 8] = a4;
      uint4 b4 = *(const uint4*)&BT[(size_t)(n0 + r) * HDIM + k0 + c * 8];
      *(uint4*)&Bs[(r * 8 + (c ^ (r & 7))) * 8] = b4;
    }
    __syncthreads();
#pragma unroll
    for (int s = 0; s < 2; ++s) {
      bf16x8 af[4], bfv[4];
#pragma unroll
      for (int i = 0; i < 4; ++i) {
        int m = wm + i * 16 + lr;
        af[i]  = *(const bf16x8*)&As[(m * 8 + ((s * 4 + lq) ^ (m & 7))) * 8];
        int n = wn + i * 16 + lr;
        bfv[i] = *(const bf16x8*)&Bs[(n * 8 + ((s * 4 + lq) ^ (n & 7))) * 8];
      }
#pragma unroll
      for (int i = 0; i < 4; ++i)
#pragma unroll
        for (int j = 0; j < 4; ++j)
          acc[i][j] = __builtin_amdgcn_mfma_f32_16x16x32_bf16(af[i], bfv[j], acc[i][j], 0, 0, 0);
    }
    __syncthreads();
  }
#pragma unroll
  for (int i = 0; i < 4; ++i)
#pragma unroll
    for (int j = 0; j < 4; ++j) {
      int col = n0 + wn + j * 16 + lr;
      float bb = b1[(size_t)e * IDIM + col];
#pragma unroll
      for (int r = 0; r < 4; ++r) {
        int rowl = m0 + wm + i * 16 + lq * 4 + r;
        if (rowl < cnt) {
          float y = acc[i][j][r] + bb;
          float g = 0.5f * y * (1.0f + erff(y * 0.70710678118654752f));
          h1[(size_t)(base + rowl) * IDIM + col] = f2bf(g);
        }
      }
    }
}

// ---------------- MoE GEMM2: h1 @ w2T[e] + b2 -> ybuf (packed rows) ----------------
__global__ __launch_bounds__(256)
void moe_gemm2_kernel(const u16* __restrict__ h1, const u16* __restrict__ w2T,
                      const float* __restrict__ b2, const int* __restrict__ counts,
                      const int* __restrict__ ebase, u16* __restrict__ ybuf)
{
  int e = blockIdx.z;
  int cnt = counts[e];
  int m0 = blockIdx.x * 128;
  if (m0 >= cnt) return;
  int n0 = blockIdx.y * 128;
  int base = ebase[e];
  __shared__ __align__(16) u16 As[128 * 64];
  __shared__ __align__(16) u16 Bs[128 * 64];
  int tid = threadIdx.x;
  const u16* BT = w2T + (size_t)e * HDIM * IDIM;   // [HDIM][IDIM]
  f32x4 acc[4][4];
#pragma unroll
  for (int i = 0; i < 4; ++i)
#pragma unroll
    for (int j = 0; j < 4; ++j) acc[i][j] = (f32x4){0.f, 0.f, 0.f, 0.f};
  int w = tid >> 6, l = tid & 63;
  int lr = l & 15, lq = l >> 4;
  int wm = (w & 1) * 64, wn = (w >> 1) * 64;
  for (int k0 = 0; k0 < IDIM; k0 += 64) {
#pragma unroll
    for (int p = 0; p < 4; ++p) {
      int flat = p * 256 + tid;
      int r = flat >> 3, c = flat & 7;
      int rowg = m0 + r;
      uint4 a4 = {0u, 0u, 0u, 0u};
      if (rowg < cnt) a4 = *(const uint4*)&h1[(size_t)(base + rowg) * IDIM + k0 + c * 8];
      *(uint4*)&As[(r * 8 + (c ^ (r & 7))) * 8] = a4;
      uint4 b4 = *(const uint4*)&BT[(size_t)(n0 + r) * IDIM + k0 + c * 8];
      *(uint4*)&Bs[(r * 8 + (c ^ (r & 7))) * 8] = b4;
    }
    __syncthreads();
#pragma unroll
    for (int s = 0; s < 2; ++s) {
      bf16x8 af[4], bfv[4];
#pragma unroll
      for (int i = 0; i < 4; ++i) {
        int m = wm + i * 16 + lr;
        af[i]  = *(const bf16x8*)&As[(m * 8 + ((s * 4 + lq) ^ (m & 7))) * 8];
        int n = wn + i * 16 + lr;
        bfv[i] = *(const bf16x8*)&Bs[(n * 8 + ((s * 4 + lq) ^ (n & 7))) * 8];
      }
#pragma unroll
      for (int i = 0; i < 4; ++i)
#pragma unroll
        for (int j = 0; j < 4; ++j)
          acc[i][j] = __builtin_amdgcn_mfma_f32_16x16x32_bf16(af[i], bfv[j], acc[i][j], 0, 0, 0);
    }
    __syncthreads();
  }
#pragma unroll
  for (int i = 0; i < 4; ++i)
#pragma unroll
    for (int j = 0; j < 4; ++j) {
      int col = n0 + wn + j * 16 + lr;
      float bb = b2[(size_t)e * HDIM + col];
#pragma unroll
      for (int r = 0; r < 4; ++r) {
        int rowl = m0 + wm + i * 16 + lq * 4 + r;
        if (rowl < cnt)
          ybuf[(size_t)(base + rowl) * HDIM + col] = f2bf(acc[i][j][r] + bb);
      }
    }
}

// ---------------- final: h + sum_k tw_k * y[row_k] -> LayerNorm -> fp32 out ----------------
__global__ __launch_bounds__(256)
void final_kernel(const float* __restrict__ h, const u16* __restrict__ ybuf,
                  const int* __restrict__ slotmap, const float* __restrict__ tw,
                  const float* __restrict__ lnw, const float* __restrict__ lnb,
                  float* __restrict__ out)
{
  int t = blockIdx.x, tid = threadIdx.x;
  int s0 = slotmap[t * 2], s1 = slotmap[t * 2 + 1];
  float w0 = tw[t * 2], w1v = tw[t * 2 + 1];
  float4 hv = ((const float4*)(h + (size_t)t * HDIM))[tid];
  float vals[4] = {hv.x, hv.y, hv.z, hv.w};
  if (s0 >= 0) {
    const u16* yr = ybuf + (size_t)s0 * HDIM + tid * 4;
#pragma unroll
    for (int j = 0; j < 4; ++j) vals[j] += w0 * bf2f(yr[j]);
  }
  if (s1 >= 0) {
    const u16* yr = ybuf + (size_t)s1 * HDIM + tid * 4;
#pragma unroll
    for (int j = 0; j < 4; ++j) vals[j] += w1v * bf2f(yr[j]);
  }
  float s = vals[0] + vals[1] + vals[2] + vals[3];
  float q2 = vals[0] * vals[0] + vals[1] * vals[1] + vals[2] * vals[2] + vals[3] * vals[3];
  __shared__ float reds[4], redq[4];
  float wsv = wave_sum(s), wqv = wave_sum(q2);
  int wid = tid >> 6, l = tid & 63;
  if (l == 0) { reds[wid] = wsv; redq[wid] = wqv; }
  __syncthreads();
  float tot = reds[0] + reds[1] + reds[2] + reds[3];
  float totq = redq[0] + redq[1] + redq[2] + redq[3];
  float mu = tot / 1024.0f;
  float var = totq / 1024.0f - mu * mu;
  float inv = 1.0f / sqrtf(var + 1e-6f);
#pragma unroll
  for (int j = 0; j < 4; ++j) {
    int c = tid * 4 + j;
    out[(size_t)t * HDIM + c] = (vals[j] - mu) * inv * lnw[c] + lnb[c];
  }
}

extern "C" void kernel_launch(void* const* d_in, const int* in_sizes, int n_in,
                              void* d_out, int out_size, void* d_ws, size_t ws_size,
                              hipStream_t stream)
{
  const float* x      = (const float*)d_in[0];
  // d_in[1] = attn_mask — applied analytically via k<=q
  const float* qw     = (const float*)d_in[2];
  const float* qb     = (const float*)d_in[3];
  const float* kw     = (const float*)d_in[4];
  const float* kb     = (const float*)d_in[5];
  const float* vw     = (const float*)d_in[6];
  const float* vb     = (const float*)d_in[7];
  const float* ow     = (const float*)d_in[8];
  const float* ob     = (const float*)d_in[9];
  const float* rms_w  = (const float*)d_in[10];
  const float* gate_w = (const float*)d_in[11];
  const float* w1     = (const float*)d_in[12];
  const float* b1     = (const float*)d_in[13];
  const float* w2     = (const float*)d_in[14];
  const float* b2     = (const float*)d_in[15];
  const float* ln_w   = (const float*)d_in[16];
  const float* ln_b   = (const float*)d_in[17];

  char* ws = (char*)d_ws;
  const size_t MB = 1024ull * 1024ull;
  // [0,16)   q, then proj
  // [16,32)  kT          \ after attn: wT (32MB, spans [16,48))
  // [32,48)  v           /
  // [48,64)  ao, then h (fp32, live to end)
  // [64,72)  hbf (bf16 h)
  // [72,104) h1  (packed, 8192 x IDIM bf16 = 32MB)
  // [104,120) ybuf (packed, 8192 x HDIM bf16 = 16MB)
  // [120,..) small
  float* qbuf   = (float*)(ws + 0 * MB);
  float* kTbuf  = (float*)(ws + 16 * MB);
  float* vbuf   = (float*)(ws + 32 * MB);
  float* aobuf  = (float*)(ws + 48 * MB);
  u16*   wT     = (u16*)(ws + 16 * MB);
  float* hbuf   = (float*)(ws + 48 * MB);
  u16*   hbf    = (u16*)(ws + 64 * MB);
  u16*   h1buf  = (u16*)(ws + 72 * MB);
  u16*   ybuf   = (u16*)(ws + 104 * MB);
  char*  sm     = ws + 120 * MB;
  int*   ti      = (int*)(sm);
  float* tw      = (float*)(sm + 32 * 1024);
  int*   eidx    = (int*)(sm + 64 * 1024);
  int*   slotmap = (int*)(sm + 128 * 1024);
  int*   counts  = (int*)(sm + 160 * 1024);
  int*   ebase   = (int*)(sm + 164 * 1024);
  float* projbuf = qbuf;

  qkv_kernel<<<dim3(NTOK / 128, HDIM / 128, 3), 256, 0, stream>>>(
      x, qw, qb, kw, kb, vw, vb, qbuf, kTbuf, vbuf);
  attn_kernel<<<NB * NHEAD * SQL / 4, 256, 0, stream>>>(qbuf, kTbuf, vbuf, aobuf);
  proj_kernel<<<dim3(NTOK / 128, HDIM / 128), 256, 0, stream>>>(aobuf, ow, ob, projbuf);
  rmsnorm_kernel<<<NTOK, 256, 0, stream>>>(x, projbuf, rms_w, hbuf, hbf);
  // w1 [e][HDIM][IDIM] -> wT [e][IDIM][HDIM]  (kT/v regions dead after attn)
  transpose_cvt_kernel<<<dim3(IDIM / 32, HDIM / 32, NEXP), 256, 0, stream>>>(
      w1, wT, HDIM, IDIM);
  router_kernel<<<NTOK / 4, 256, 0, stream>>>(hbuf, gate_w, ti, tw);
  scan_kernel<<<1, 64, 0, stream>>>(ti, eidx, counts, slotmap, ebase);
  moe_gemm1_kernel<<<dim3(CAPACITY / 128, IDIM / 128, NEXP), 256, 0, stream>>>(
      hbf, wT, b1, eidx, counts, ebase, h1buf);
  // w2 [e][IDIM][HDIM] -> wT [e][HDIM][IDIM]  (after gemm1 consumed w1T)
  transpose_cvt_kernel<<<dim3(HDIM / 32, IDIM / 32, NEXP), 256, 0, stream>>>(
      w2, wT, IDIM, HDIM);
  moe_gemm2_kernel<<<dim3(CAPACITY / 128, HDIM / 128, NEXP), 256, 0, stream>>>(
      h1buf, wT, b2, counts, ebase, ybuf);
  final_kernel<<<NTOK, 256, 0, stream>>>(hbuf, ybuf, slotmap, tw, ln_w, ln_b,
                                         (float*)d_out);
}

// Round 5
// 1407.272 us; speedup vs baseline: 2.0671x; 1.1900x over previous
//
#include <hip/hip_runtime.h>

#define NB 4
#define SQL 1024
#define HDIM 1024
#define NHEAD 16
#define HEADD 64
#define NEXP 8
#define IDIM 2048
#define NTOK (NB*SQL)
#define CAPACITY 2048
#define ATT_SCALE 0.125f

typedef unsigned short u16;
typedef __attribute__((ext_vector_type(8))) short bf16x8;
typedef __attribute__((ext_vector_type(4))) float f32x4;

__device__ __forceinline__ u16 f2bf(float f) {
  union { float f; unsigned u; } x; x.f = f;
  unsigned r = (x.u + 0x7fffu + ((x.u >> 16) & 1u)) >> 16;
  return (u16)r;
}
__device__ __forceinline__ float bf2f(u16 b) {
  union { unsigned u; float f; } x; x.u = ((unsigned)b) << 16;
  return x.f;
}
__device__ __forceinline__ float wave_sum(float v) {
#pragma unroll
  for (int off = 32; off > 0; off >>= 1) v += __shfl_xor(v, off);
  return v;
}

// ---------------- fp32 128x128 tiled GEMM core (vector ALU, exact fp32) ----------------
__device__ __forceinline__ void gemm_f32_128(const float* __restrict__ A, int lda,
                                             const float* __restrict__ Bm, int ldb,
                                             int Kd, int m0, int n0, float acc[8][8])
{
  __shared__ float As[16 * 132];   // [k][m]
  __shared__ float Bs[16 * 132];   // [k][n]
  int tid = threadIdx.x;
  int tx = tid & 15, ty = tid >> 4;
  for (int k0 = 0; k0 < Kd; k0 += 16) {
#pragma unroll
    for (int p = 0; p < 2; ++p) {
      int flat = p * 256 + tid;
      int m = flat >> 2, kc = (flat & 3) * 4;
      float4 av = *(const float4*)&A[(size_t)(m0 + m) * lda + k0 + kc];
      As[(kc + 0) * 132 + m] = av.x;
      As[(kc + 1) * 132 + m] = av.y;
      As[(kc + 2) * 132 + m] = av.z;
      As[(kc + 3) * 132 + m] = av.w;
      int kk = flat >> 5, nc = (flat & 31) * 4;
      float4 bv = *(const float4*)&Bm[(size_t)(k0 + kk) * ldb + n0 + nc];
      *(float4*)&Bs[kk * 132 + nc] = bv;
    }
    __syncthreads();
#pragma unroll
    for (int kk = 0; kk < 16; ++kk) {
      float a[8], b[8];
      *(float4*)&a[0] = *(const float4*)&As[kk * 132 + ty * 8];
      *(float4*)&a[4] = *(const float4*)&As[kk * 132 + ty * 8 + 4];
      *(float4*)&b[0] = *(const float4*)&Bs[kk * 132 + tx * 8];
      *(float4*)&b[4] = *(const float4*)&Bs[kk * 132 + tx * 8 + 4];
#pragma unroll
      for (int i = 0; i < 8; ++i)
#pragma unroll
        for (int j = 0; j < 8; ++j)
          acc[i][j] = fmaf(a[i], b[j], acc[i][j]);
    }
    __syncthreads();
  }
}

// ---------------- QKV projection: x@W+b, q/k/v all stored [B*NH][S][HD] ----------------
__global__ __launch_bounds__(256)
void qkv_kernel(const float* __restrict__ x,
                const float* __restrict__ wq, const float* __restrict__ bq,
                const float* __restrict__ wk, const float* __restrict__ bk,
                const float* __restrict__ wv, const float* __restrict__ bv,
                float* __restrict__ q, float* __restrict__ k, float* __restrict__ v)
{
  int mode = blockIdx.z;
  const float* W   = (mode == 0) ? wq : (mode == 1) ? wk : wv;
  const float* bia = (mode == 0) ? bq : (mode == 1) ? bk : bv;
  float* dst       = (mode == 0) ? q : (mode == 1) ? k : v;
  float acc[8][8];
#pragma unroll
  for (int i = 0; i < 8; ++i)
#pragma unroll
    for (int j = 0; j < 8; ++j) acc[i][j] = 0.f;
  int m0 = blockIdx.x * 128, n0 = blockIdx.y * 128;
  gemm_f32_128(x, HDIM, W, HDIM, HDIM, m0, n0, acc);
  int tx = threadIdx.x & 15, ty = threadIdx.x >> 4;
#pragma unroll
  for (int i = 0; i < 8; ++i) {
    int tg = m0 + ty * 8 + i;
    int bb = tg >> 10, s = tg & 1023;
#pragma unroll
    for (int j = 0; j < 8; ++j) {
      int cg = n0 + tx * 8 + j;
      int hh = cg >> 6, d = cg & 63;
      int bh = bb * NHEAD + hh;
      dst[((size_t)bh * SQL + s) * HEADD + d] = acc[i][j] + bia[cg];
    }
  }
}

// ---------------- O-projection ----------------
__global__ __launch_bounds__(256)
void proj_kernel(const float* __restrict__ ao, const float* __restrict__ ow,
                 const float* __restrict__ ob, float* __restrict__ out)
{
  float acc[8][8];
#pragma unroll
  for (int i = 0; i < 8; ++i)
#pragma unroll
    for (int j = 0; j < 8; ++j) acc[i][j] = 0.f;
  int m0 = blockIdx.x * 128, n0 = blockIdx.y * 128;
  gemm_f32_128(ao, HDIM, ow, HDIM, HDIM, m0, n0, acc);
  int tx = threadIdx.x & 15, ty = threadIdx.x >> 4;
#pragma unroll
  for (int i = 0; i < 8; ++i)
#pragma unroll
    for (int j = 0; j < 8; ++j) {
      int cg = n0 + tx * 8 + j;
      out[(size_t)(m0 + ty * 8 + i) * HDIM + cg] = acc[i][j] + ob[cg];
    }
}

// ---------------- flash attention, fp32, 64-query tile per block ----------------
// LDS: Qs[d][q], KPs[d][k] (reused as P^T[k][q]), Vs[k][d]; online softmax.
__global__ __launch_bounds__(256)
void attn_kernel(const float* __restrict__ q, const float* __restrict__ k,
                 const float* __restrict__ v, float* __restrict__ ao)
{
  __shared__ float Qs[64 * 68];
  __shared__ float KPs[64 * 68];
  __shared__ float Vs[64 * 68];
  int id = blockIdx.x;
  int qt = id & 15, bh = id >> 4;     // qt varies fastest -> XCD/work mix
  int q0 = qt * 64;
  int tid = threadIdx.x;
  int tx = tid & 15, ty = tid >> 4;
  const float* qb = q + ((size_t)bh * SQL + q0) * HEADD;
#pragma unroll
  for (int p = 0; p < 4; ++p) {
    int flat = p * 256 + tid;
    int r = flat >> 4, c4 = (flat & 15) * 4;
    float4 t = *(const float4*)&qb[r * HEADD + c4];
    Qs[(c4 + 0) * 68 + r] = t.x;
    Qs[(c4 + 1) * 68 + r] = t.y;
    Qs[(c4 + 2) * 68 + r] = t.z;
    Qs[(c4 + 3) * 68 + r] = t.w;
  }
  float m[4], lsum[4], O[4][4];
#pragma unroll
  for (int i = 0; i < 4; ++i) {
    m[i] = -1e30f; lsum[i] = 0.f;
#pragma unroll
    for (int j = 0; j < 4; ++j) O[i][j] = 0.f;
  }
  for (int kb = 0; kb <= q0; kb += 64) {
    __syncthreads();                    // prev PV done; Qs visible on first iter
    const float* kbp = k + ((size_t)bh * SQL + kb) * HEADD;
    const float* vbp = v + ((size_t)bh * SQL + kb) * HEADD;
#pragma unroll
    for (int p = 0; p < 4; ++p) {
      int flat = p * 256 + tid;
      int r = flat >> 4, c4 = (flat & 15) * 4;
      float4 t = *(const float4*)&kbp[r * HEADD + c4];
      KPs[(c4 + 0) * 68 + r] = t.x;
      KPs[(c4 + 1) * 68 + r] = t.y;
      KPs[(c4 + 2) * 68 + r] = t.z;
      KPs[(c4 + 3) * 68 + r] = t.w;
      float4 tv = *(const float4*)&vbp[r * HEADD + c4];
      *(float4*)&Vs[r * 68 + c4] = tv;
    }
    __syncthreads();
    float sacc[4][4];
#pragma unroll
    for (int i = 0; i < 4; ++i)
#pragma unroll
      for (int j = 0; j < 4; ++j) sacc[i][j] = 0.f;
#pragma unroll 4
    for (int kk = 0; kk < 64; ++kk) {
      float a[4], b[4];
      *(float4*)a = *(const float4*)&Qs[kk * 68 + ty * 4];
      *(float4*)b = *(const float4*)&KPs[kk * 68 + tx * 4];
#pragma unroll
      for (int i = 0; i < 4; ++i)
#pragma unroll
        for (int j = 0; j < 4; ++j)
          sacc[i][j] = fmaf(a[i], b[j], sacc[i][j]);
    }
    __syncthreads();                    // all waves done reading KPs
    float pfrag[4][4];
#pragma unroll
    for (int i = 0; i < 4; ++i) {
      int srow = q0 + ty * 4 + i;
      float sv[4], rm = -1e30f;
#pragma unroll
      for (int j = 0; j < 4; ++j) {
        int col = kb + tx * 4 + j;
        sv[j] = (col <= srow) ? sacc[i][j] * ATT_SCALE : -1e30f;
        rm = fmaxf(rm, sv[j]);
      }
#pragma unroll
      for (int off = 8; off > 0; off >>= 1) rm = fmaxf(rm, __shfl_xor(rm, off));
      float mnew = fmaxf(m[i], rm);
      float alpha = expf(m[i] - mnew);
      float rl = 0.f;
#pragma unroll
      for (int j = 0; j < 4; ++j) {
        float pv = (sv[j] > -1e29f) ? expf(sv[j] - mnew) : 0.f;
        pfrag[i][j] = pv; rl += pv;
      }
#pragma unroll
      for (int off = 8; off > 0; off >>= 1) rl += __shfl_xor(rl, off);
      lsum[i] = lsum[i] * alpha + rl;
      m[i] = mnew;
#pragma unroll
      for (int j = 0; j < 4; ++j) O[i][j] *= alpha;
    }
    // P^T into KPs: [k][q]
#pragma unroll
    for (int i = 0; i < 4; ++i)
#pragma unroll
      for (int j = 0; j < 4; ++j)
        KPs[(tx * 4 + j) * 68 + ty * 4 + i] = pfrag[i][j];
    __syncthreads();
#pragma unroll 4
    for (int kk = 0; kk < 64; ++kk) {
      float a[4], b[4];
      *(float4*)a = *(const float4*)&KPs[kk * 68 + ty * 4];
      *(float4*)b = *(const float4*)&Vs[kk * 68 + tx * 4];
#pragma unroll
      for (int i = 0; i < 4; ++i)
#pragma unroll
        for (int j = 0; j < 4; ++j)
          O[i][j] = fmaf(a[i], b[j], O[i][j]);
    }
  }
  int b = bh >> 4, hh = bh & 15;
#pragma unroll
  for (int i = 0; i < 4; ++i) {
    float invl = 1.0f / lsum[i];
    int srow = q0 + ty * 4 + i;
    float4 o = {O[i][0] * invl, O[i][1] * invl, O[i][2] * invl, O[i][3] * invl};
    *(float4*)&ao[((size_t)(b * SQL + srow)) * HDIM + hh * HEADD + tx * 4] = o;
  }
}

// ---------------- residual + RMSNorm (fp32 h out + bf16 copy) ----------------
__global__ __launch_bounds__(256)
void rmsnorm_kernel(const float* __restrict__ x, const float* __restrict__ p,
                    const float* __restrict__ w, float* __restrict__ out,
                    u16* __restrict__ outbf)
{
  int t = blockIdx.x, tid = threadIdx.x;
  float4 xv = ((const float4*)(x + (size_t)t * HDIM))[tid];
  float4 pv = ((const float4*)(p + (size_t)t * HDIM))[tid];
  float4 s = {xv.x + pv.x, xv.y + pv.y, xv.z + pv.z, xv.w + pv.w};
  float ss = s.x * s.x + s.y * s.y + s.z * s.z + s.w * s.w;
  __shared__ float red[4];
  float wsv = wave_sum(ss);
  int wid = tid >> 6, l = tid & 63;
  if (l == 0) red[wid] = wsv;
  __syncthreads();
  float tot = red[0] + red[1] + red[2] + red[3];
  float inv = 1.0f / sqrtf(tot / (float)HDIM + 1e-6f);
  float4 wv = ((const float4*)w)[tid];
  float4 o = {s.x * inv * wv.x, s.y * inv * wv.y, s.z * inv * wv.z, s.w * inv * wv.w};
  ((float4*)(out + (size_t)t * HDIM))[tid] = o;
  ushort4 ob = {f2bf(o.x), f2bf(o.y), f2bf(o.z), f2bf(o.w)};
  ((ushort4*)(outbf + (size_t)t * HDIM))[tid] = ob;
}

// ---------------- transpose+convert: in fp32 [e][R][C] -> out bf16 [e][C][R] ----------------
__global__ __launch_bounds__(256)
void transpose_cvt_kernel(const float* __restrict__ in, u16* __restrict__ out,
                          int R, int C)
{
  int e = blockIdx.z;
  const float* ine = in + (size_t)e * R * C;
  u16* oute = out + (size_t)e * R * C;
  __shared__ u16 Ts[32 * 34];
  int tx = threadIdx.x & 31, ty = threadIdx.x >> 5;
  int r0 = blockIdx.y * 32, c0 = blockIdx.x * 32;
#pragma unroll
  for (int qq = 0; qq < 4; ++qq) {
    int rr = ty + qq * 8;
    Ts[tx * 34 + rr] = f2bf(ine[(size_t)(r0 + rr) * C + c0 + tx]);
  }
  __syncthreads();
#pragma unroll
  for (int qq = 0; qq < 4; ++qq) {
    int cc = ty + qq * 8;
    oute[(size_t)(c0 + cc) * R + r0 + tx] = Ts[cc * 34 + tx];
  }
}

// ---------------- router: logits, softmax, top-2, weight norm ----------------
__global__ __launch_bounds__(256)
void router_kernel(const float* __restrict__ h, const float* __restrict__ gw,
                   int* __restrict__ ti, float* __restrict__ tw)
{
  int wid = threadIdx.x >> 6, l = threadIdx.x & 63;
  int t = blockIdx.x * 4 + wid;
  const float* hr = h + (size_t)t * HDIM;
  float hv[16];
#pragma unroll
  for (int j = 0; j < 16; ++j) hv[j] = hr[l + 64 * j];
  float lg[NEXP];
#pragma unroll
  for (int e = 0; e < NEXP; ++e) {
    const float* g = gw + (size_t)e * HDIM;
    float p = 0.f;
#pragma unroll
    for (int j = 0; j < 16; ++j) p += hv[j] * g[l + 64 * j];
    lg[e] = wave_sum(p);
  }
  if (l == 0) {
    int i1 = 0; float m1 = lg[0];
#pragma unroll
    for (int e = 1; e < NEXP; ++e) if (lg[e] > m1) { m1 = lg[e]; i1 = e; }
    int i2 = 0; float m2 = -1e30f;
#pragma unroll
    for (int e = 0; e < NEXP; ++e) if (e != i1 && lg[e] > m2) { m2 = lg[e]; i2 = e; }
    float se = 0.f;
#pragma unroll
    for (int e = 0; e < NEXP; ++e) se += expf(lg[e] - m1);
    float p1 = 1.0f / se;
    float p2 = expf(m2 - m1) / se;
    float denom = p1 + p2 + 1e-20f;
    tw[t * 2]     = p1 / denom * 0.5f;
    tw[t * 2 + 1] = p2 / denom * 0.5f;
    ti[t * 2]     = i1;
    ti[t * 2 + 1] = i2;
  }
}

// ---------------- deterministic capacity scan + packed-row bases ----------------
__global__ void scan_kernel(const int* __restrict__ ti, int* __restrict__ eidx,
                            int* __restrict__ counts, int* __restrict__ slotmap,
                            int* __restrict__ ebase)
{
  int l = threadIdx.x;
  int base[NEXP] = {0, 0, 0, 0, 0, 0, 0, 0};
  unsigned long long below = (l == 0) ? 0ull : ((~0ull) >> (64 - l));
  for (int c2 = 0; c2 < (NTOK * 2) / 64; ++c2) {
    int f = c2 * 64 + l;
    int e = ti[f];
    int mypos = 0;
#pragma unroll
    for (int e0 = 0; e0 < NEXP; ++e0) {
      unsigned long long mm = __ballot(e == e0);
      if (e == e0) mypos = base[e0] + __popcll(mm & below);
      base[e0] += __popcll(mm);
    }
    int slot;
    if (mypos < CAPACITY) {
      slot = e * CAPACITY + mypos;
      eidx[slot] = f >> 1;
    } else slot = -1;
    slotmap[f] = slot;
  }
  int eb[NEXP]; int run = 0;
#pragma unroll
  for (int e = 0; e < NEXP; ++e) {
    eb[e] = run;
    run += (base[e] < CAPACITY) ? base[e] : CAPACITY;
  }
  if (l < NEXP) {
    counts[l] = (base[l] < CAPACITY) ? base[l] : CAPACITY;
    ebase[l] = eb[l];
  }
  for (int c2 = 0; c2 < (NTOK * 2) / 64; ++c2) {
    int f = c2 * 64 + l;
    int vv = slotmap[f];
    if (vv >= 0) slotmap[f] = eb[vv >> 11] + (vv & (CAPACITY - 1));
  }
}

// ---------------- MoE GEMM1: gathered hbf @ w1T[e] + b1 -> gelu -> h1 (packed rows) ------
__global__ __launch_bounds__(256)
void moe_gemm1_kernel(const u16* __restrict__ hbf, const u16* __restrict__ w1T,
                      const float* __restrict__ b1, const int* __restrict__ eidx,
                      const int* __restrict__ counts, const int* __restrict__ ebase,
                      u16* __restrict__ h1)
{
  int e = blockIdx.z;
  int cnt = counts[e];
  int m0 = blockIdx.x * 128;
  if (m0 >= cnt) return;
  int n0 = blockIdx.y * 128;
  int base = ebase[e];
  __shared__ __align__(16) u16 As[128 * 64];
  __shared__ __align__(16) u16 Bs[128 * 64];
  __shared__ int rowtok[128];
  int tid = threadIdx.x;
  if (tid < 128) {
    int r = m0 + tid;
    rowtok[tid] = (r < cnt) ? eidx[e * CAPACITY + r] : -1;
  }
  __syncthreads();
  const u16* BT = w1T + (size_t)e * IDIM * HDIM;
  f32x4 acc[4][4];
#pragma unroll
  for (int i = 0; i < 4; ++i)
#pragma unroll
    for (int j = 0; j < 4; ++j) acc[i][j] = (f32x4){0.f, 0.f, 0.f, 0.f};
  int w = tid >> 6, l = tid & 63;
  int lr = l & 15, lq = l >> 4;
  int wm = (w & 1) * 64, wn = (w >> 1) * 64;
  for (int k0 = 0; k0 < HDIM; k0 += 64) {
#pragma unroll
    for (int p = 0; p < 4; ++p) {
      int flat = p * 256 + tid;
      int r = flat >> 3, c = flat & 7;
      int tok = rowtok[r];
      uint4 a4 = {0u, 0u, 0u, 0u};
      if (tok >= 0) a4 = *(const uint4*)&hbf[(size_t)tok * HDIM + k0 + c * 8];
      *(uint4*)&As[(r * 8 + (c ^ (r & 7))) * 8] = a4;
      uint4 b4 = *(const uint4*)&BT[(size_t)(n0 + r) * HDIM + k0 + c * 8];
      *(uint4*)&Bs[(r * 8 + (c ^ (r & 7))) * 8] = b4;
    }
    __syncthreads();
#pragma unroll
    for (int s = 0; s < 2; ++s) {
      bf16x8 af[4], bfv[4];
#pragma unroll
      for (int i = 0; i < 4; ++i) {
        int mloc = wm + i * 16 + lr;
        af[i]  = *(const bf16x8*)&As[(mloc * 8 + ((s * 4 + lq) ^ (mloc & 7))) * 8];
        int n = wn + i * 16 + lr;
        bfv[i] = *(const bf16x8*)&Bs[(n * 8 + ((s * 4 + lq) ^ (n & 7))) * 8];
      }
#pragma unroll
      for (int i = 0; i < 4; ++i)
#pragma unroll
        for (int j = 0; j < 4; ++j)
          acc[i][j] = __builtin_amdgcn_mfma_f32_16x16x32_bf16(af[i], bfv[j], acc[i][j], 0, 0, 0);
    }
    __syncthreads();
  }
#pragma unroll
  for (int i = 0; i < 4; ++i)
#pragma unroll
    for (int j = 0; j < 4; ++j) {
      int col = n0 + wn + j * 16 + lr;
      float bb = b1[(size_t)e * IDIM + col];
#pragma unroll
      for (int r = 0; r < 4; ++r) {
        int rowl = m0 + wm + i * 16 + lq * 4 + r;
        if (rowl < cnt) {
          float y = acc[i][j][r] + bb;
          float g = 0.5f * y * (1.0f + erff(y * 0.70710678118654752f));
          h1[(size_t)(base + rowl) * IDIM + col] = f2bf(g);
        }
      }
    }
}

// ---------------- MoE GEMM2: h1 @ w2T[e] + b2 -> ybuf (packed rows) ----------------
__global__ __launch_bounds__(256)
void moe_gemm2_kernel(const u16* __restrict__ h1, const u16* __restrict__ w2T,
                      const float* __restrict__ b2, const int* __restrict__ counts,
                      const int* __restrict__ ebase, u16* __restrict__ ybuf)
{
  int e = blockIdx.z;
  int cnt = counts[e];
  int m0 = blockIdx.x * 128;
  if (m0 >= cnt) return;
  int n0 = blockIdx.y * 128;
  int base = ebase[e];
  __shared__ __align__(16) u16 As[128 * 64];
  __shared__ __align__(16) u16 Bs[128 * 64];
  int tid = threadIdx.x;
  const u16* BT = w2T + (size_t)e * HDIM * IDIM;
  f32x4 acc[4][4];
#pragma unroll
  for (int i = 0; i < 4; ++i)
#pragma unroll
    for (int j = 0; j < 4; ++j) acc[i][j] = (f32x4){0.f, 0.f, 0.f, 0.f};
  int w = tid >> 6, l = tid & 63;
  int lr = l & 15, lq = l >> 4;
  int wm = (w & 1) * 64, wn = (w >> 1) * 64;
  for (int k0 = 0; k0 < IDIM; k0 += 64) {
#pragma unroll
    for (int p = 0; p < 4; ++p) {
      int flat = p * 256 + tid;
      int r = flat >> 3, c = flat & 7;
      int rowg = m0 + r;
      uint4 a4 = {0u, 0u, 0u, 0u};
      if (rowg < cnt) a4 = *(const uint4*)&h1[(size_t)(base + rowg) * IDIM + k0 + c * 8];
      *(uint4*)&As[(r * 8 + (c ^ (r & 7))) * 8] = a4;
      uint4 b4 = *(const uint4*)&BT[(size_t)(n0 + r) * IDIM + k0 + c * 8];
      *(uint4*)&Bs[(r * 8 + (c ^ (r & 7))) * 8] = b4;
    }
    __syncthreads();
#pragma unroll
    for (int s = 0; s < 2; ++s) {
      bf16x8 af[4], bfv[4];
#pragma unroll
      for (int i = 0; i < 4; ++i) {
        int mloc = wm + i * 16 + lr;
        af[i]  = *(const bf16x8*)&As[(mloc * 8 + ((s * 4 + lq) ^ (mloc & 7))) * 8];
        int n = wn + i * 16 + lr;
        bfv[i] = *(const bf16x8*)&Bs[(n * 8 + ((s * 4 + lq) ^ (n & 7))) * 8];
      }
#pragma unroll
      for (int i = 0; i < 4; ++i)
#pragma unroll
        for (int j = 0; j < 4; ++j)
          acc[i][j] = __builtin_amdgcn_mfma_f32_16x16x32_bf16(af[i], bfv[j], acc[i][j], 0, 0, 0);
    }
    __syncthreads();
  }
#pragma unroll
  for (int i = 0; i < 4; ++i)
#pragma unroll
    for (int j = 0; j < 4; ++j) {
      int col = n0 + wn + j * 16 + lr;
      float bb = b2[(size_t)e * HDIM + col];
#pragma unroll
      for (int r = 0; r < 4; ++r) {
        int rowl = m0 + wm + i * 16 + lq * 4 + r;
        if (rowl < cnt)
          ybuf[(size_t)(base + rowl) * HDIM + col] = f2bf(acc[i][j][r] + bb);
      }
    }
}

// ---------------- final: h + sum_k tw_k * y[row_k] -> LayerNorm -> fp32 out ----------------
__global__ __launch_bounds__(256)
void final_kernel(const float* __restrict__ h, const u16* __restrict__ ybuf,
                  const int* __restrict__ slotmap, const float* __restrict__ tw,
                  const float* __restrict__ lnw, const float* __restrict__ lnb,
                  float* __restrict__ out)
{
  int t = blockIdx.x, tid = threadIdx.x;
  int s0 = slotmap[t * 2], s1 = slotmap[t * 2 + 1];
  float w0 = tw[t * 2], w1v = tw[t * 2 + 1];
  float4 hv = ((const float4*)(h + (size_t)t * HDIM))[tid];
  float vals[4] = {hv.x, hv.y, hv.z, hv.w};
  if (s0 >= 0) {
    const u16* yr = ybuf + (size_t)s0 * HDIM + tid * 4;
#pragma unroll
    for (int j = 0; j < 4; ++j) vals[j] += w0 * bf2f(yr[j]);
  }
  if (s1 >= 0) {
    const u16* yr = ybuf + (size_t)s1 * HDIM + tid * 4;
#pragma unroll
    for (int j = 0; j < 4; ++j) vals[j] += w1v * bf2f(yr[j]);
  }
  float s = vals[0] + vals[1] + vals[2] + vals[3];
  float q2 = vals[0] * vals[0] + vals[1] * vals[1] + vals[2] * vals[2] + vals[3] * vals[3];
  __shared__ float reds[4], redq[4];
  float wsv = wave_sum(s), wqv = wave_sum(q2);
  int wid = tid >> 6, l = tid & 63;
  if (l == 0) { reds[wid] = wsv; redq[wid] = wqv; }
  __syncthreads();
  float tot = reds[0] + reds[1] + reds[2] + reds[3];
  float totq = redq[0] + redq[1] + redq[2] + redq[3];
  float mu = tot / 1024.0f;
  float var = totq / 1024.0f - mu * mu;
  float inv = 1.0f / sqrtf(var + 1e-6f);
#pragma unroll
  for (int j = 0; j < 4; ++j) {
    int c = tid * 4 + j;
    out[(size_t)t * HDIM + c] = (vals[j] - mu) * inv * lnw[c] + lnb[c];
  }
}

extern "C" void kernel_launch(void* const* d_in, const int* in_sizes, int n_in,
                              void* d_out, int out_size, void* d_ws, size_t ws_size,
                              hipStream_t stream)
{
  const float* x      = (const float*)d_in[0];
  const float* qw     = (const float*)d_in[2];
  const float* qb     = (const float*)d_in[3];
  const float* kw     = (const float*)d_in[4];
  const float* kb     = (const float*)d_in[5];
  const float* vw     = (const float*)d_in[6];
  const float* vb     = (const float*)d_in[7];
  const float* ow     = (const float*)d_in[8];
  const float* ob     = (const float*)d_in[9];
  const float* rms_w  = (const float*)d_in[10];
  const float* gate_w = (const float*)d_in[11];
  const float* w1     = (const float*)d_in[12];
  const float* b1     = (const float*)d_in[13];
  const float* w2     = (const float*)d_in[14];
  const float* b2     = (const float*)d_in[15];
  const float* ln_w   = (const float*)d_in[16];
  const float* ln_b   = (const float*)d_in[17];

  char* ws = (char*)d_ws;
  const size_t MB = 1024ull * 1024ull;
  float* qbuf   = (float*)(ws + 0 * MB);
  float* kbuf   = (float*)(ws + 16 * MB);
  float* vbuf   = (float*)(ws + 32 * MB);
  float* aobuf  = (float*)(ws + 48 * MB);
  u16*   wT     = (u16*)(ws + 16 * MB);
  float* hbuf   = (float*)(ws + 48 * MB);
  u16*   hbf    = (u16*)(ws + 64 * MB);
  u16*   h1buf  = (u16*)(ws + 72 * MB);
  u16*   ybuf   = (u16*)(ws + 104 * MB);
  char*  sm     = ws + 120 * MB;
  int*   ti      = (int*)(sm);
  float* tw      = (float*)(sm + 32 * 1024);
  int*   eidx    = (int*)(sm + 64 * 1024);
  int*   slotmap = (int*)(sm + 128 * 1024);
  int*   counts  = (int*)(sm + 160 * 1024);
  int*   ebase   = (int*)(sm + 164 * 1024);
  float* projbuf = qbuf;

  qkv_kernel<<<dim3(NTOK / 128, HDIM / 128, 3), 256, 0, stream>>>(
      x, qw, qb, kw, kb, vw, vb, qbuf, kbuf, vbuf);
  attn_kernel<<<NB * NHEAD * (SQL / 64), 256, 0, stream>>>(qbuf, kbuf, vbuf, aobuf);
  proj_kernel<<<dim3(NTOK / 128, HDIM / 128), 256, 0, stream>>>(aobuf, ow, ob, projbuf);
  rmsnorm_kernel<<<NTOK, 256, 0, stream>>>(x, projbuf, rms_w, hbuf, hbf);
  transpose_cvt_kernel<<<dim3(IDIM / 32, HDIM / 32, NEXP), 256, 0, stream>>>(
      w1, wT, HDIM, IDIM);
  router_kernel<<<NTOK / 4, 256, 0, stream>>>(hbuf, gate_w, ti, tw);
  scan_kernel<<<1, 64, 0, stream>>>(ti, eidx, counts, slotmap, ebase);
  moe_gemm1_kernel<<<dim3(CAPACITY / 128, IDIM / 128, NEXP), 256, 0, stream>>>(
      hbf, wT, b1, eidx, counts, ebase, h1buf);
  transpose_cvt_kernel<<<dim3(HDIM / 32, IDIM / 32, NEXP), 256, 0, stream>>>(
      w2, wT, IDIM, HDIM);
  moe_gemm2_kernel<<<dim3(CAPACITY / 128, HDIM / 128, NEXP), 256, 0, stream>>>(
      h1buf, wT, b2, counts, ebase, ybuf);
  final_kernel<<<NTOK, 256, 0, stream>>>(hbuf, ybuf, slotmap, tw, ln_w, ln_b,
                                         (float*)d_out);
}